// Round 14
// baseline (96.284 us; speedup 1.0000x reference)
//
#include <hip/hip_runtime.h>
#include <hip/hip_bf16.h>

#define NB   8192   // batch
#define NS   10     // neighbor seq len
#define NT   3      // node types
#define NN   65536  // table size
#define ND   128    // embed dim
#define NL   2      // layers
#define ROWS 32     // batch rows per block

typedef __attribute__((ext_vector_type(8))) short bf16x8;
typedef __attribute__((ext_vector_type(4))) float f32x4;

__device__ __forceinline__ unsigned int pk2(float lo, float hi) {
    unsigned int r;
    asm("v_cvt_pk_bf16_f32 %0, %1, %2" : "=v"(r) : "v"(lo), "v"(hi));
    return r;
}
// tanh(x) = 1 - 2/(exp2(2*log2e*x)+1)
__device__ __forceinline__ float tanh_f(float x) {
    float e, r;
    asm("v_exp_f32 %0, %1" : "=v"(e) : "v"(x * 2.88539004f));
    asm("v_rcp_f32 %0, %1" : "=v"(r) : "v"(e + 1.0f));
    return fmaf(-2.0f, r, 1.0f);
}
// Barrier with LDS-only drain: global (vmcnt) loads stay in flight across it.
__device__ __forceinline__ void bar_lgkm() {
    asm volatile("s_waitcnt lgkmcnt(0)\n\ts_barrier" ::: "memory");
}

// ---------------------------------------------------------------------------
// RNN kernel: grid = NL*NT*256 blocks, 128 threads (2 waves = e-halves).
// Block owns (l, t, 32 rows); wave computes a 64-e slice for all 32 rows.
// Rationale (r8-r13 law): wall ~ wave_steps x 4.4Kcy / resident_waves, and
// residency is reg-pinned at ~2/SIMD -> halve wave_steps with 2x-fat waves
// (64 MFMA/step). Barrier couples only 2 waves. W2=[Wih;Whh] 64-e slice =
// Af[4][8] (128 regs). X staged once/step per block; X and H double-buffered
// in LDS ([32][128] bf16, XOR-swizzled 16B chunks); ONE lgkm-only barrier per
// step; register gather prefetch stays in flight across it (vmcnt undrained).
// NO launch_bounds min-waves (r7/r10: cap below working set = spills).
// ---------------------------------------------------------------------------
__global__ __launch_bounds__(128)
void rnn_kernel(const float* __restrict__ emb, const float* __restrict__ Wih,
                const float* __restrict__ Whh, const float* __restrict__ bih,
                const float* __restrict__ bhh, const int* __restrict__ nidx,
                float* __restrict__ agg)
{
    // [X p0 | X p1 | H p0 | H p1], 8 KB each = 32 KB
    __shared__ __align__(16) char lds[4 * 8192];

    const int bid = blockIdx.x;                 // NL*NT*(NB/ROWS)
    const int l   = bid / (NT * (NB / ROWS));
    const int t   = (bid / (NB / ROWS)) % NT;
    const int b0  = (bid % (NB / ROWS)) * ROWS;

    const int tid  = threadIdx.x;
    const int wv   = tid >> 6;       // e-half 0/1
    const int lane = tid & 63;
    const int l16  = lane & 15;
    const int lg   = lane >> 4;
    const int e0   = wv * 64;
    const int rx   = l16 & 7;        // read/write swizzle key (row%8 == l16%8)

    char* xb = lds;
    char* hb = lds + 16384;

    // staging geometry: 4 threads per row, 4 chunks (8 f32 each) per thread
    const int srow = tid >> 2;       // 0..31
    const int sq   = tid & 3;        // chunk quartet
    const int ssw  = srow & 7;

    // ---- rolling neighbor-index prefetch ----
    const int* ip = nidx + ((size_t)t * NB + b0 + srow) * NS;
    int idx_nxt = ip[1];

    // ---- prefetch s=0 gather (lands while W-fragments are built) ----
    float4 P[8];
    {
        const float* src = emb + ((size_t)t * NN + ip[0]) * ND + sq * 32;
        #pragma unroll
        for (int c = 0; c < 4; ++c) {
            P[2 * c]     = *(const float4*)(src + c * 8);
            P[2 * c + 1] = *(const float4*)(src + c * 8 + 4);
        }
    }

    const float* Wih_lt = Wih + (size_t)(l * NT + t) * ND * ND;
    const float* Whh_lt = Whh + (size_t)(l * NT + t) * ND * ND;
    const float* bih_lt = bih + (size_t)(l * NT + t) * ND;
    const float* bhh_lt = bhh + (size_t)(l * NT + t) * ND;

    // ---- A-fragments: rows e = e0 + mt*16 + l16, k-chunk kc (kc<4: Wih) ----
    bf16x8 Af[4][8];
    #pragma unroll
    for (int mt = 0; mt < 4; ++mt) {
        #pragma unroll
        for (int kc = 0; kc < 8; ++kc) {
            const float* Wsrc = (kc < 4) ? Wih_lt : Whh_lt;
            const float* srcp = Wsrc + (size_t)(e0 + mt * 16 + l16) * ND + (kc & 3) * 32 + lg * 8;
            float4 p0 = *(const float4*)(srcp);
            float4 p1 = *(const float4*)(srcp + 4);
            int4 a;
            a.x = (int)pk2(p0.x, p0.y);
            a.y = (int)pk2(p0.z, p0.w);
            a.z = (int)pk2(p1.x, p1.y);
            a.w = (int)pk2(p1.z, p1.w);
            Af[mt][kc] = *(bf16x8*)&a;
        }
    }

    // bias folded into MFMA C-init
    f32x4 biasv[4];
    #pragma unroll
    for (int mt = 0; mt < 4; ++mt) {
        int e = e0 + mt * 16 + lg * 4;
        float4 bi = *(const float4*)(bih_lt + e);
        float4 bh = *(const float4*)(bhh_lt + e);
        biasv[mt][0] = bi.x + bh.x;
        biasv[mt][1] = bi.y + bh.y;
        biasv[mt][2] = bi.z + bh.z;
        biasv[mt][3] = bi.w + bh.w;
    }

    f32x4 zero4; zero4[0] = 0.f; zero4[1] = 0.f; zero4[2] = 0.f; zero4[3] = 0.f;
    f32x4 Ag[2][4];
    #pragma unroll
    for (int nt = 0; nt < 2; ++nt)
        #pragma unroll
        for (int mt = 0; mt < 4; ++mt) Ag[nt][mt] = zero4;

    #pragma unroll
    for (int s = 0; s < NS; ++s) {
        const int par  = (s & 1) * 8192;
        const int ppar = ((s + 1) & 1) * 8192;

        // ---- pack prefetched X_s -> swizzled LDS (4x ds_write_b128) ----
        #pragma unroll
        for (int c = 0; c < 4; ++c) {
            int4 pk;
            pk.x = (int)pk2(P[2 * c].x,     P[2 * c].y);
            pk.y = (int)pk2(P[2 * c].z,     P[2 * c].w);
            pk.z = (int)pk2(P[2 * c + 1].x, P[2 * c + 1].y);
            pk.w = (int)pk2(P[2 * c + 1].z, P[2 * c + 1].w);
            *(int4*)(xb + srow * 256 + (((sq * 4 + c) ^ ssw) << 4) + par) = pk;
        }
        // ---- issue next-step gather; stays in flight across the barrier ----
        if (s + 1 < NS) {
            const float* src = emb + ((size_t)t * NN + idx_nxt) * ND + sq * 32;
            #pragma unroll
            for (int c = 0; c < 4; ++c) {
                P[2 * c]     = *(const float4*)(src + c * 8);
                P[2 * c + 1] = *(const float4*)(src + c * 8 + 4);
            }
            if (s + 2 < NS) idx_nxt = ip[s + 2];
        }
        bar_lgkm();   // X_s and H_{s-1} visible to both waves; vmcnt in flight

        // ---- acc = bias + W2-slice x Z-rows (K=256: X then H) ----
        f32x4 acc[2][4];
        #pragma unroll
        for (int nt = 0; nt < 2; ++nt)
            #pragma unroll
            for (int mt = 0; mt < 4; ++mt) acc[nt][mt] = biasv[mt];

        #pragma unroll
        for (int nt = 0; nt < 2; ++nt)
            #pragma unroll
            for (int c = 0; c < 4; ++c) {
                bf16x8 bf = *(const bf16x8*)(xb + nt * 4096 + l16 * 256
                                             + (((c * 4 + lg) ^ rx) << 4) + par);
                #pragma unroll
                for (int mt = 0; mt < 4; ++mt)
                    acc[nt][mt] = __builtin_amdgcn_mfma_f32_16x16x32_bf16(Af[mt][c], bf, acc[nt][mt], 0, 0, 0);
            }
        if (s > 0) {
            #pragma unroll
            for (int nt = 0; nt < 2; ++nt)
                #pragma unroll
                for (int c = 0; c < 4; ++c) {
                    bf16x8 bf = *(const bf16x8*)(hb + nt * 4096 + l16 * 256
                                                 + (((c * 4 + lg) ^ rx) << 4) + ppar);
                    #pragma unroll
                    for (int mt = 0; mt < 4; ++mt)
                        acc[nt][mt] = __builtin_amdgcn_mfma_f32_16x16x32_bf16(Af[mt][c + 4], bf, acc[nt][mt], 0, 0, 0);
                }
        }

        // ---- tanh + agg accumulate + packed H writeback ----
        #pragma unroll
        for (int nt = 0; nt < 2; ++nt)
            #pragma unroll
            for (int mt = 0; mt < 4; ++mt) {
                f32x4 h;
                #pragma unroll
                for (int i = 0; i < 4; ++i)
                    h[i] = tanh_f(acc[nt][mt][i]);
                Ag[nt][mt] += h;
                int2 pk;
                pk.x = (int)pk2(h[0], h[1]);
                pk.y = (int)pk2(h[2], h[3]);
                int es = e0 + mt * 16 + lg * 4;           // 4 consecutive e, row nt*16+l16
                *(int2*)(hb + nt * 4096 + l16 * 256
                         + ((((es >> 3)) ^ rx) << 4) + (lg & 1) * 8 + par) = pk;
            }
    }

    // agg[l][t][b][e]: lane writes float4 of 4 consecutive e at its rows
    float* aggp = agg + ((size_t)(l * NT + t) * NB + b0) * ND;
    #pragma unroll
    for (int nt = 0; nt < 2; ++nt)
        #pragma unroll
        for (int mt = 0; mt < 4; ++mt) {
            f32x4 v = Ag[nt][mt] * 0.1f;
            *(f32x4*)(aggp + (size_t)(nt * 16 + l16) * ND + e0 + mt * 16 + lg * 4) = v;
        }
}

// ---------------------------------------------------------------------------
// Attention: one wave per batch row (lane covers d and d+64). 5 dots via
// shuffle reduce, softmax(4), weighted sum, leaky_relu. 2048 blocks x 256.
// ---------------------------------------------------------------------------
__global__ __launch_bounds__(256)
void att_kernel(const float* __restrict__ emb, const int* __restrict__ ids,
                const float* __restrict__ w_att, const float* __restrict__ agg,
                float* __restrict__ cur, const int l)
{
    const int wid  = threadIdx.x >> 6;
    const int lane = threadIdx.x & 63;
    const int b    = blockIdx.x * 4 + wid;

    const float* waH  = w_att + l * 2 * ND;
    const float* waT  = waH + ND;
    const float* crow = (l == 0) ? (emb + (size_t)ids[b] * ND) : (cur + (size_t)b * ND);
    const float* ab   = agg + ((size_t)(l * NT) * NB + b) * ND;   // + tt*NB*ND

    const float c1 = crow[lane], c2 = crow[lane + 64];
    const float h1 = waH[lane],  h2 = waH[lane + 64];
    const float t1 = waT[lane],  t2 = waT[lane + 64];
    float g1[3], g2[3];
    #pragma unroll
    for (int tt = 0; tt < 3; ++tt) {
        g1[tt] = ab[(size_t)tt * NB * ND + lane];
        g2[tt] = ab[(size_t)tt * NB * ND + lane + 64];
    }

    float dH = c1 * h1 + c2 * h2;
    float dc = c1 * t1 + c2 * t2;
    float d0 = g1[0] * t1 + g2[0] * t2;
    float d1 = g1[1] * t1 + g2[1] * t2;
    float d2 = g1[2] * t1 + g2[2] * t2;
    #pragma unroll
    for (int off = 32; off > 0; off >>= 1) {
        dH += __shfl_xor(dH, off);
        dc += __shfl_xor(dc, off);
        d0 += __shfl_xor(d0, off);
        d1 += __shfl_xor(d1, off);
        d2 += __shfl_xor(d2, off);
    }

    float s0 = dH + dc, s1 = dH + d0, s2 = dH + d1, s3 = dH + d2;
    float m  = fmaxf(fmaxf(s0, s1), fmaxf(s2, s3));
    float q0 = __expf(s0 - m), q1 = __expf(s1 - m), q2 = __expf(s2 - m), q3 = __expf(s3 - m);
    float inv = __fdividef(1.0f, q0 + q1 + q2 + q3);
    float w0 = q0 * inv, w1 = q1 * inv, w2 = q2 * inv, w3 = q3 * inv;

    float o1 = w0 * c1 + w1 * g1[0] + w2 * g1[1] + w3 * g1[2];
    float o2 = w0 * c2 + w1 * g2[0] + w2 * g2[1] + w3 * g2[2];
    o1 = (o1 > 0.f) ? o1 : 0.01f * o1;
    o2 = (o2 > 0.f) ? o2 : 0.01f * o2;

    float* orow = cur + (size_t)b * ND;
    orow[lane]      = o1;
    orow[lane + 64] = o2;
}

extern "C" void kernel_launch(void* const* d_in, const int* in_sizes, int n_in,
                              void* d_out, int out_size, void* d_ws, size_t ws_size,
                              hipStream_t stream)
{
    const float* emb  = (const float*)d_in[0];
    const float* Wih  = (const float*)d_in[1];
    const float* Whh  = (const float*)d_in[2];
    const float* bih  = (const float*)d_in[3];
    const float* bhh  = (const float*)d_in[4];
    const float* watt = (const float*)d_in[5];
    const int*   ids  = (const int*)d_in[6];
    const int*   nidx = (const int*)d_in[7];

    float* cur = (float*)d_out;            // [B][D] fp32, final output
    float* agg = (float*)d_ws;             // [L][T][B][D] fp32 = 25 MB

    rnn_kernel<<<dim3(NL * NT * (NB / ROWS)), dim3(128), 0, stream>>>(emb, Wih, Whh, bih, bhh, nidx, agg);
    att_kernel<<<dim3(NB / 4), dim3(256), 0, stream>>>(emb, ids, watt, agg, cur, 0);
    att_kernel<<<dim3(NB / 4), dim3(256), 0, stream>>>(emb, ids, watt, agg, cur, 1);
}

// Round 17
// 87.947 us; speedup vs baseline: 1.0948x; 1.0948x over previous
//
#include <hip/hip_runtime.h>
#include <hip/hip_bf16.h>

#define NB   8192   // batch
#define NS   10     // neighbor seq len
#define NT   3      // node types
#define NN   65536  // table size
#define ND   128    // embed dim
#define NL   2      // layers
#define ROWS 64     // batch rows per block

typedef __attribute__((ext_vector_type(8))) short bf16x8;
typedef __attribute__((ext_vector_type(4))) float f32x4;

__device__ __forceinline__ unsigned int pk2(float lo, float hi) {
    unsigned int r;
    asm("v_cvt_pk_bf16_f32 %0, %1, %2" : "=v"(r) : "v"(lo), "v"(hi));
    return r;
}
// tanh(x) = 1 - 2/(exp2(2*log2e*x)+1)
__device__ __forceinline__ float tanh_f(float x) {
    float e, r;
    asm("v_exp_f32 %0, %1" : "=v"(e) : "v"(x * 2.88539004f));
    asm("v_rcp_f32 %0, %1" : "=v"(r) : "v"(e + 1.0f));
    return fmaf(-2.0f, r, 1.0f);
}
// Barrier with LDS-only drain: global (vmcnt) loads stay in flight across it.
__device__ __forceinline__ void bar_lgkm() {
    asm volatile("s_waitcnt lgkmcnt(0)\n\ts_barrier" ::: "memory");
}

// ---------------------------------------------------------------------------
// RNN kernel: grid = NL*NT*128 blocks (3/CU exact), 256 thr (4 waves = e-32
// slices of one layer). Block owns (l, t, 64 rows) -> fat-by-rows: 64 MFMA
// per wave-step with Af only 64 regs (r14's fat-by-e hit the 256-reg clamp).
// wave_steps/CU halves vs r9 (240 -> 120) at the same register tier.
// Per-nt phased inner loop: {4 X reads -> 8 MFMA -> [4 H reads -> 8 MFMA]
// -> tanh -> H-write} keeps only acc[2] live and spreads LDS ops (convoy
// relief). X and H double-buffered in LDS ([64][128] bf16, XOR-swizzled 16B
// chunks); ONE lgkm-only barrier per step; register gather prefetch stays in
// flight across it (vmcnt undrained). NO launch_bounds min-waves (r7/r10).
// ---------------------------------------------------------------------------
__global__ __launch_bounds__(256)
void rnn_kernel(const float* __restrict__ emb, const float* __restrict__ Wih,
                const float* __restrict__ Whh, const float* __restrict__ bih,
                const float* __restrict__ bhh, const int* __restrict__ nidx,
                float* __restrict__ agg)
{
    // [X p0 | X p1 | H p0 | H p1], 16 KB each = 64 KB
    __shared__ __align__(16) char lds[4 * 16384];

    const int bid = blockIdx.x;                 // NL*NT*(NB/ROWS)
    const int l   = bid / (NT * (NB / ROWS));
    const int t   = (bid / (NB / ROWS)) % NT;
    const int b0  = (bid % (NB / ROWS)) * ROWS;

    const int tid  = threadIdx.x;
    const int wv   = tid >> 6;       // e-slice 0..3
    const int lane = tid & 63;
    const int l16  = lane & 15;
    const int lg   = lane >> 4;
    const int e0   = wv * 32;
    const int rx   = l16 & 7;        // read/H-write swizzle key (row%8==l16%8)

    char* xb = lds;
    char* hb = lds + 32768;

    // staging geometry: 4 threads per row, 32 f32 (4 bf16x8 chunks) each
    const int srow = tid >> 2;       // 0..63
    const int sq   = tid & 3;
    const int ssw  = srow & 7;

    // ---- rolling neighbor-index prefetch (protect the 256-reg clamp) ----
    const int* ip = nidx + ((size_t)t * NB + b0 + srow) * NS;
    int idx_nxt = ip[1];

    // ---- prefetch s=0 gather (lands while W-fragments are built) ----
    float4 P[8];
    {
        const float* src = emb + ((size_t)t * NN + ip[0]) * ND + sq * 32;
        #pragma unroll
        for (int c = 0; c < 4; ++c) {
            P[2 * c]     = *(const float4*)(src + c * 8);
            P[2 * c + 1] = *(const float4*)(src + c * 8 + 4);
        }
    }

    const float* Wih_lt = Wih + (size_t)(l * NT + t) * ND * ND;
    const float* Whh_lt = Whh + (size_t)(l * NT + t) * ND * ND;
    const float* bih_lt = bih + (size_t)(l * NT + t) * ND;
    const float* bhh_lt = bhh + (size_t)(l * NT + t) * ND;

    // ---- A-fragments: rows e = e0 + mt*16 + l16, k-chunk kc (kc<4: Wih) ----
    bf16x8 Af[2][8];
    #pragma unroll
    for (int mt = 0; mt < 2; ++mt) {
        #pragma unroll
        for (int kc = 0; kc < 8; ++kc) {
            const float* Wsrc = (kc < 4) ? Wih_lt : Whh_lt;
            const float* srcp = Wsrc + (size_t)(e0 + mt * 16 + l16) * ND + (kc & 3) * 32 + lg * 8;
            float4 p0 = *(const float4*)(srcp);
            float4 p1 = *(const float4*)(srcp + 4);
            int4 a;
            a.x = (int)pk2(p0.x, p0.y);
            a.y = (int)pk2(p0.z, p0.w);
            a.z = (int)pk2(p1.x, p1.y);
            a.w = (int)pk2(p1.z, p1.w);
            Af[mt][kc] = *(bf16x8*)&a;
        }
    }

    // bias folded into MFMA C-init
    f32x4 biasv[2];
    #pragma unroll
    for (int mt = 0; mt < 2; ++mt) {
        int e = e0 + mt * 16 + lg * 4;
        float4 bi = *(const float4*)(bih_lt + e);
        float4 bh = *(const float4*)(bhh_lt + e);
        biasv[mt][0] = bi.x + bh.x;
        biasv[mt][1] = bi.y + bh.y;
        biasv[mt][2] = bi.z + bh.z;
        biasv[mt][3] = bi.w + bh.w;
    }

    // read chunk offsets (shared across nt; nt*4096 added as immediate)
    int rdch[4];
    #pragma unroll
    for (int c = 0; c < 4; ++c)
        rdch[c] = l16 * 256 + (((c * 4 + lg) ^ rx) << 4);
    // H-write offset: es = e0 + mt*16 + lg*4 (mt*2 chunk delta as immediate)
    const int hw0 = l16 * 256 + ((((e0 >> 3) + (lg >> 1)) ^ rx) << 4) + (lg & 1) * 8;
    const int hw1 = l16 * 256 + ((((e0 >> 3) + 2 + (lg >> 1)) ^ rx) << 4) + (lg & 1) * 8;

    f32x4 zero4; zero4[0] = 0.f; zero4[1] = 0.f; zero4[2] = 0.f; zero4[3] = 0.f;
    f32x4 Ag[4][2];
    #pragma unroll
    for (int nt = 0; nt < 4; ++nt) { Ag[nt][0] = zero4; Ag[nt][1] = zero4; }

    #pragma unroll
    for (int s = 0; s < NS; ++s) {
        const int par  = (s & 1) * 16384;
        const int ppar = ((s + 1) & 1) * 16384;

        // ---- pack prefetched X_s -> swizzled LDS (4x ds_write_b128) ----
        #pragma unroll
        for (int c = 0; c < 4; ++c) {
            int4 pk;
            pk.x = (int)pk2(P[2 * c].x,     P[2 * c].y);
            pk.y = (int)pk2(P[2 * c].z,     P[2 * c].w);
            pk.z = (int)pk2(P[2 * c + 1].x, P[2 * c + 1].y);
            pk.w = (int)pk2(P[2 * c + 1].z, P[2 * c + 1].w);
            *(int4*)(xb + srow * 256 + (((sq * 4 + c) ^ ssw) << 4) + par) = pk;
        }
        // ---- issue next-step gather; stays in flight across the barrier ----
        if (s + 1 < NS) {
            const float* src = emb + ((size_t)t * NN + idx_nxt) * ND + sq * 32;
            #pragma unroll
            for (int c = 0; c < 4; ++c) {
                P[2 * c]     = *(const float4*)(src + c * 8);
                P[2 * c + 1] = *(const float4*)(src + c * 8 + 4);
            }
            if (s + 2 < NS) idx_nxt = ip[s + 2];
        }
        bar_lgkm();   // X_s and H_{s-1} visible to all 4 waves; vmcnt in flight

        // ---- per-nt phased: reads -> MFMA -> tanh -> H-write ----
        #pragma unroll
        for (int nt = 0; nt < 4; ++nt) {
            f32x4 acc0 = biasv[0], acc1 = biasv[1];
            #pragma unroll
            for (int c = 0; c < 4; ++c) {
                bf16x8 bf = *(const bf16x8*)(xb + nt * 4096 + rdch[c] + par);
                acc0 = __builtin_amdgcn_mfma_f32_16x16x32_bf16(Af[0][c], bf, acc0, 0, 0, 0);
                acc1 = __builtin_amdgcn_mfma_f32_16x16x32_bf16(Af[1][c], bf, acc1, 0, 0, 0);
            }
            if (s > 0) {
                #pragma unroll
                for (int c = 0; c < 4; ++c) {
                    bf16x8 bf = *(const bf16x8*)(hb + nt * 4096 + rdch[c] + ppar);
                    acc0 = __builtin_amdgcn_mfma_f32_16x16x32_bf16(Af[0][c + 4], bf, acc0, 0, 0, 0);
                    acc1 = __builtin_amdgcn_mfma_f32_16x16x32_bf16(Af[1][c + 4], bf, acc1, 0, 0, 0);
                }
            }
            f32x4 h0, h1;
            #pragma unroll
            for (int i = 0; i < 4; ++i) {
                h0[i] = tanh_f(acc0[i]);
                h1[i] = tanh_f(acc1[i]);
            }
            Ag[nt][0] += h0;
            Ag[nt][1] += h1;
            int2 pk0, pk1;
            pk0.x = (int)pk2(h0[0], h0[1]);
            pk0.y = (int)pk2(h0[2], h0[3]);
            pk1.x = (int)pk2(h1[0], h1[1]);
            pk1.y = (int)pk2(h1[2], h1[3]);
            *(int2*)(hb + nt * 4096 + hw0 + par) = pk0;
            *(int2*)(hb + nt * 4096 + hw1 + par) = pk1;
        }
    }

    // agg[l][t][b][e]: lane writes float4 of 4 consecutive e at its rows
    float* aggp = agg + ((size_t)(l * NT + t) * NB + b0) * ND;
    #pragma unroll
    for (int nt = 0; nt < 4; ++nt)
        #pragma unroll
        for (int mt = 0; mt < 2; ++mt) {
            f32x4 v = Ag[nt][mt] * 0.1f;
            *(f32x4*)(aggp + (size_t)(nt * 16 + l16) * ND + e0 + mt * 16 + lg * 4) = v;
        }
}

// ---------------------------------------------------------------------------
// Attention: one wave per batch row (lane covers d and d+64). 5 dots via
// shuffle reduce, softmax(4), weighted sum, leaky_relu. 2048 blocks x 256.
// ---------------------------------------------------------------------------
__global__ __launch_bounds__(256)
void att_kernel(const float* __restrict__ emb, const int* __restrict__ ids,
                const float* __restrict__ w_att, const float* __restrict__ agg,
                float* __restrict__ cur, const int l)
{
    const int wid  = threadIdx.x >> 6;
    const int lane = threadIdx.x & 63;
    const int b    = blockIdx.x * 4 + wid;

    const float* waH  = w_att + l * 2 * ND;
    const float* waT  = waH + ND;
    const float* crow = (l == 0) ? (emb + (size_t)ids[b] * ND) : (cur + (size_t)b * ND);
    const float* ab   = agg + ((size_t)(l * NT) * NB + b) * ND;   // + tt*NB*ND

    const float c1 = crow[lane], c2 = crow[lane + 64];
    const float h1 = waH[lane],  h2 = waH[lane + 64];
    const float t1 = waT[lane],  t2 = waT[lane + 64];
    float g1[3], g2[3];
    #pragma unroll
    for (int tt = 0; tt < 3; ++tt) {
        g1[tt] = ab[(size_t)tt * NB * ND + lane];
        g2[tt] = ab[(size_t)tt * NB * ND + lane + 64];
    }

    float dH = c1 * h1 + c2 * h2;
    float dc = c1 * t1 + c2 * t2;
    float d0 = g1[0] * t1 + g2[0] * t2;
    float d1 = g1[1] * t1 + g2[1] * t2;
    float d2 = g1[2] * t1 + g2[2] * t2;
    #pragma unroll
    for (int off = 32; off > 0; off >>= 1) {
        dH += __shfl_xor(dH, off);
        dc += __shfl_xor(dc, off);
        d0 += __shfl_xor(d0, off);
        d1 += __shfl_xor(d1, off);
        d2 += __shfl_xor(d2, off);
    }

    float s0 = dH + dc, s1 = dH + d0, s2 = dH + d1, s3 = dH + d2;
    float m  = fmaxf(fmaxf(s0, s1), fmaxf(s2, s3));
    float q0 = __expf(s0 - m), q1 = __expf(s1 - m), q2 = __expf(s2 - m), q3 = __expf(s3 - m);
    float inv = __fdividef(1.0f, q0 + q1 + q2 + q3);
    float w0 = q0 * inv, w1 = q1 * inv, w2 = q2 * inv, w3 = q3 * inv;

    float o1 = w0 * c1 + w1 * g1[0] + w2 * g1[1] + w3 * g1[2];
    float o2 = w0 * c2 + w1 * g2[0] + w2 * g2[1] + w3 * g2[2];
    o1 = (o1 > 0.f) ? o1 : 0.01f * o1;
    o2 = (o2 > 0.f) ? o2 : 0.01f * o2;

    float* orow = cur + (size_t)b * ND;
    orow[lane]      = o1;
    orow[lane + 64] = o2;
}

extern "C" void kernel_launch(void* const* d_in, const int* in_sizes, int n_in,
                              void* d_out, int out_size, void* d_ws, size_t ws_size,
                              hipStream_t stream)
{
    const float* emb  = (const float*)d_in[0];
    const float* Wih  = (const float*)d_in[1];
    const float* Whh  = (const float*)d_in[2];
    const float* bih  = (const float*)d_in[3];
    const float* bhh  = (const float*)d_in[4];
    const float* watt = (const float*)d_in[5];
    const int*   ids  = (const int*)d_in[6];
    const int*   nidx = (const int*)d_in[7];

    float* cur = (float*)d_out;            // [B][D] fp32, final output
    float* agg = (float*)d_ws;             // [L][T][B][D] fp32 = 25 MB

    rnn_kernel<<<dim3(NL * NT * (NB / ROWS)), dim3(256), 0, stream>>>(emb, Wih, Whh, bih, bhh, nidx, agg);
    att_kernel<<<dim3(NB / 4), dim3(256), 0, stream>>>(emb, ids, watt, agg, cur, 0);
    att_kernel<<<dim3(NB / 4), dim3(256), 0, stream>>>(emb, ids, watt, agg, cur, 1);
}

// Round 18
// 78.451 us; speedup vs baseline: 1.2273x; 1.1210x over previous
//
#include <hip/hip_runtime.h>
#include <hip/hip_bf16.h>

#define NB   8192   // batch
#define NS   10     // neighbor seq len
#define NT   3      // node types
#define NN   65536  // table size
#define ND   128    // embed dim
#define NL   2      // layers
#define ROWS 32     // batch rows per block

typedef __attribute__((ext_vector_type(8))) short bf16x8;
typedef __attribute__((ext_vector_type(4))) float f32x4;

__device__ __forceinline__ unsigned int pk2(float lo, float hi) {
    unsigned int r;
    asm("v_cvt_pk_bf16_f32 %0, %1, %2" : "=v"(r) : "v"(lo), "v"(hi));
    return r;
}
// tanh(x) = 1 - 2/(exp2(2*log2e*x)+1)
__device__ __forceinline__ float tanh_f(float x) {
    float e, r;
    asm("v_exp_f32 %0, %1" : "=v"(e) : "v"(x * 2.88539004f));
    asm("v_rcp_f32 %0, %1" : "=v"(r) : "v"(e + 1.0f));
    return fmaf(-2.0f, r, 1.0f);
}
// Barrier with LDS-only drain: global (vmcnt) loads stay in flight across it.
__device__ __forceinline__ void bar_lgkm() {
    asm volatile("s_waitcnt lgkmcnt(0)\n\ts_barrier" ::: "memory");
}

// ---------------------------------------------------------------------------
// RNN kernel (r9 structure, ROLLED s-loop): grid = NT*256 blocks, 512 thr
// (8 waves = layer(2) x e-32(4)). Block owns (t, 32 rows), BOTH layers; X
// gathered+staged once/step for all 8 waves. KEY CHANGE vs r9/r13: s-loop is
// #pragma unroll 1 -- full unroll was the +40-VGPR bloat (r8 rolled = 84 VGPR
// = 16-waves/CU tier, eff 9.2 waves; r9/r13 unrolled = 124+16 > 128-tier,
// eff 6.4). Target: unified total <= 128 -> double residency at r9's
// wave_steps. X + per-layer H double-buffered in LDS ([32][128] bf16,
// XOR-swizzled 16B chunks); ONE lgkm-only barrier per step; register gather
// prefetch in flight across it (vmcnt undrained). NO min-waves clause.
// ---------------------------------------------------------------------------
__global__ __launch_bounds__(512)
void rnn_kernel(const float* __restrict__ emb, const float* __restrict__ Wih,
                const float* __restrict__ Whh, const float* __restrict__ bih,
                const float* __restrict__ bhh, const int* __restrict__ nidx,
                float* __restrict__ agg)
{
    // [X p0 | X p1 | H(l0) p0 | H(l0) p1 | H(l1) p0 | H(l1) p1], 8 KB each
    __shared__ __align__(16) char lds[6 * 8192];

    const int bid = blockIdx.x;                 // NT * (NB/ROWS)
    const int t   = bid / (NB / ROWS);
    const int b0  = (bid % (NB / ROWS)) * ROWS;

    const int tid  = threadIdx.x;
    const int wv   = tid >> 6;
    const int lay  = wv >> 2;        // layer 0/1
    const int lane = tid & 63;
    const int l16  = lane & 15;
    const int lg   = lane >> 4;
    const int e0   = (wv & 3) * 32;  // e-slice within layer
    const int rx   = l16 & 7;        // read-swizzle key (rows stride 16)

    char* xb = lds;
    char* hb = lds + 16384 + lay * 16384;

    // staging geometry: 16 threads per row, 8 floats (one 16B bf16 chunk) each
    const int srow  = tid >> 4;      // 0..31
    const int sq    = tid & 15;      // chunk index
    const int xaddr = srow * 256 + ((sq ^ (srow & 7)) << 4);

    // ---- rolling neighbor-index prefetch (1 live reg) ----
    const int* ip = nidx + ((size_t)t * NB + b0 + srow) * NS;
    int idx_nxt = ip[1];

    // ---- prefetch s=0 gather (lands while W-fragments are built) ----
    float4 P0, P1;
    {
        const float* src = emb + ((size_t)t * NN + ip[0]) * ND + sq * 8;
        P0 = *(const float4*)(src);
        P1 = *(const float4*)(src + 4);
    }

    const float* Wih_lt = Wih + (size_t)(lay * NT + t) * ND * ND;
    const float* Whh_lt = Whh + (size_t)(lay * NT + t) * ND * ND;
    const float* bih_lt = bih + (size_t)(lay * NT + t) * ND;
    const float* bhh_lt = bhh + (size_t)(lay * NT + t) * ND;

    // ---- A-fragments: rows e = e0 + mt*16 + l16, k-chunk kc (kc<4: Wih) ----
    bf16x8 Af[2][8];
    #pragma unroll
    for (int mt = 0; mt < 2; ++mt) {
        #pragma unroll
        for (int kc = 0; kc < 8; ++kc) {
            const float* Wsrc = (kc < 4) ? Wih_lt : Whh_lt;
            const float* srcp = Wsrc + (size_t)(e0 + mt * 16 + l16) * ND + (kc & 3) * 32 + lg * 8;
            float4 p0 = *(const float4*)(srcp);
            float4 p1 = *(const float4*)(srcp + 4);
            int4 a;
            a.x = (int)pk2(p0.x, p0.y);
            a.y = (int)pk2(p0.z, p0.w);
            a.z = (int)pk2(p1.x, p1.y);
            a.w = (int)pk2(p1.z, p1.w);
            Af[mt][kc] = *(bf16x8*)&a;
        }
    }

    // bias folded into MFMA C-init
    f32x4 biasv[2];
    #pragma unroll
    for (int mt = 0; mt < 2; ++mt) {
        int e = e0 + mt * 16 + lg * 4;
        float4 bi = *(const float4*)(bih_lt + e);
        float4 bh = *(const float4*)(bhh_lt + e);
        biasv[mt][0] = bi.x + bh.x;
        biasv[mt][1] = bi.y + bh.y;
        biasv[mt][2] = bi.z + bh.z;
        biasv[mt][3] = bi.w + bh.w;
    }

    // minimal precomputed LDS addressing (nt / parity folded at use sites)
    const int rowb = l16 * 256;
    int rdch[4];                     // read chunk offsets, shared X/H
    #pragma unroll
    for (int c = 0; c < 4; ++c)
        rdch[c] = ((c * 4 + lg) ^ rx) << 4;
    const int hw0 = ((((e0 >> 3) + (lg >> 1)) ^ rx) << 4) + (lg & 1) * 8;
    const int hw1 = ((((e0 >> 3) + 2 + (lg >> 1)) ^ rx) << 4) + (lg & 1) * 8;

    f32x4 zero4; zero4[0] = 0.f; zero4[1] = 0.f; zero4[2] = 0.f; zero4[3] = 0.f;
    f32x4 Ag[2][2];
    #pragma unroll
    for (int nt = 0; nt < 2; ++nt) { Ag[nt][0] = zero4; Ag[nt][1] = zero4; }

    #pragma unroll 1
    for (int s = 0; s < NS; ++s) {
        const int par  = (s & 1) * 8192;          // uniform -> SGPR
        const int ppar = 8192 - par;

        // ---- pack prefetched X_s -> swizzled LDS store (1x ds_write_b128) ----
        {
            int4 pk;
            pk.x = (int)pk2(P0.x, P0.y);
            pk.y = (int)pk2(P0.z, P0.w);
            pk.z = (int)pk2(P1.x, P1.y);
            pk.w = (int)pk2(P1.z, P1.w);
            *(int4*)(xb + xaddr + par) = pk;
        }
        // ---- issue next-step gather; stays in flight across the barrier ----
        if (s + 1 < NS) {
            const float* src = emb + ((size_t)t * NN + idx_nxt) * ND + sq * 8;
            P0 = *(const float4*)(src);
            P1 = *(const float4*)(src + 4);
            idx_nxt = ip[(s + 2 < NS) ? s + 2 : 0];
        }
        bar_lgkm();   // X_s and H_{s-1} visible to all 8 waves; vmcnt in flight

        // ---- acc = bias + W2-slice x Z-rows (K=256: X then H of own layer) ----
        f32x4 acc[2][2];
        #pragma unroll
        for (int nt = 0; nt < 2; ++nt) { acc[nt][0] = biasv[0]; acc[nt][1] = biasv[1]; }

        #pragma unroll
        for (int nt = 0; nt < 2; ++nt)
            #pragma unroll
            for (int c = 0; c < 4; ++c) {
                bf16x8 bf = *(const bf16x8*)(xb + rowb + rdch[c] + nt * 4096 + par);
                acc[nt][0] = __builtin_amdgcn_mfma_f32_16x16x32_bf16(Af[0][c], bf, acc[nt][0], 0, 0, 0);
                acc[nt][1] = __builtin_amdgcn_mfma_f32_16x16x32_bf16(Af[1][c], bf, acc[nt][1], 0, 0, 0);
            }
        if (s > 0) {
            #pragma unroll
            for (int nt = 0; nt < 2; ++nt)
                #pragma unroll
                for (int c = 0; c < 4; ++c) {
                    bf16x8 bf = *(const bf16x8*)(hb + rowb + rdch[c] + nt * 4096 + ppar);
                    acc[nt][0] = __builtin_amdgcn_mfma_f32_16x16x32_bf16(Af[0][c + 4], bf, acc[nt][0], 0, 0, 0);
                    acc[nt][1] = __builtin_amdgcn_mfma_f32_16x16x32_bf16(Af[1][c + 4], bf, acc[nt][1], 0, 0, 0);
                }
        }

        // ---- tanh + agg accumulate + packed H writeback (other H buffer) ----
        #pragma unroll
        for (int nt = 0; nt < 2; ++nt) {
            f32x4 h0, h1;
            #pragma unroll
            for (int i = 0; i < 4; ++i) {
                h0[i] = tanh_f(acc[nt][0][i]);
                h1[i] = tanh_f(acc[nt][1][i]);
            }
            Ag[nt][0] += h0;
            Ag[nt][1] += h1;
            int2 pk0, pk1;
            pk0.x = (int)pk2(h0[0], h0[1]);
            pk0.y = (int)pk2(h0[2], h0[3]);
            pk1.x = (int)pk2(h1[0], h1[1]);
            pk1.y = (int)pk2(h1[2], h1[3]);
            *(int2*)(hb + rowb + hw0 + nt * 4096 + par) = pk0;
            *(int2*)(hb + rowb + hw1 + nt * 4096 + par) = pk1;
        }
    }

    // agg[l][t][b][e]: lane writes float4 of 4 consecutive e at its rows
    float* aggp = agg + ((size_t)(lay * NT + t) * NB + b0) * ND;
    #pragma unroll
    for (int nt = 0; nt < 2; ++nt)
        #pragma unroll
        for (int mt = 0; mt < 2; ++mt) {
            f32x4 v = Ag[nt][mt] * 0.1f;
            *(f32x4*)(aggp + (size_t)(nt * 16 + l16) * ND + e0 + mt * 16 + lg * 4) = v;
        }
}

// ---------------------------------------------------------------------------
// Attention: one wave per batch row (lane covers d and d+64). 5 dots via
// shuffle reduce, softmax(4), weighted sum, leaky_relu. 2048 blocks x 256.
// ---------------------------------------------------------------------------
__global__ __launch_bounds__(256)
void att_kernel(const float* __restrict__ emb, const int* __restrict__ ids,
                const float* __restrict__ w_att, const float* __restrict__ agg,
                float* __restrict__ cur, const int l)
{
    const int wid  = threadIdx.x >> 6;
    const int lane = threadIdx.x & 63;
    const int b    = blockIdx.x * 4 + wid;

    const float* waH  = w_att + l * 2 * ND;
    const float* waT  = waH + ND;
    const float* crow = (l == 0) ? (emb + (size_t)ids[b] * ND) : (cur + (size_t)b * ND);
    const float* ab   = agg + ((size_t)(l * NT) * NB + b) * ND;   // + tt*NB*ND

    const float c1 = crow[lane], c2 = crow[lane + 64];
    const float h1 = waH[lane],  h2 = waH[lane + 64];
    const float t1 = waT[lane],  t2 = waT[lane + 64];
    float g1[3], g2[3];
    #pragma unroll
    for (int tt = 0; tt < 3; ++tt) {
        g1[tt] = ab[(size_t)tt * NB * ND + lane];
        g2[tt] = ab[(size_t)tt * NB * ND + lane + 64];
    }

    float dH = c1 * h1 + c2 * h2;
    float dc = c1 * t1 + c2 * t2;
    float d0 = g1[0] * t1 + g2[0] * t2;
    float d1 = g1[1] * t1 + g2[1] * t2;
    float d2 = g1[2] * t1 + g2[2] * t2;
    #pragma unroll
    for (int off = 32; off > 0; off >>= 1) {
        dH += __shfl_xor(dH, off);
        dc += __shfl_xor(dc, off);
        d0 += __shfl_xor(d0, off);
        d1 += __shfl_xor(d1, off);
        d2 += __shfl_xor(d2, off);
    }

    float s0 = dH + dc, s1 = dH + d0, s2 = dH + d1, s3 = dH + d2;
    float m  = fmaxf(fmaxf(s0, s1), fmaxf(s2, s3));
    float q0 = __expf(s0 - m), q1 = __expf(s1 - m), q2 = __expf(s2 - m), q3 = __expf(s3 - m);
    float inv = __fdividef(1.0f, q0 + q1 + q2 + q3);
    float w0 = q0 * inv, w1 = q1 * inv, w2 = q2 * inv, w3 = q3 * inv;

    float o1 = w0 * c1 + w1 * g1[0] + w2 * g1[1] + w3 * g1[2];
    float o2 = w0 * c2 + w1 * g2[0] + w2 * g2[1] + w3 * g2[2];
    o1 = (o1 > 0.f) ? o1 : 0.01f * o1;
    o2 = (o2 > 0.f) ? o2 : 0.01f * o2;

    float* orow = cur + (size_t)b * ND;
    orow[lane]      = o1;
    orow[lane + 64] = o2;
}

extern "C" void kernel_launch(void* const* d_in, const int* in_sizes, int n_in,
                              void* d_out, int out_size, void* d_ws, size_t ws_size,
                              hipStream_t stream)
{
    const float* emb  = (const float*)d_in[0];
    const float* Wih  = (const float*)d_in[1];
    const float* Whh  = (const float*)d_in[2];
    const float* bih  = (const float*)d_in[3];
    const float* bhh  = (const float*)d_in[4];
    const float* watt = (const float*)d_in[5];
    const int*   ids  = (const int*)d_in[6];
    const int*   nidx = (const int*)d_in[7];

    float* cur = (float*)d_out;            // [B][D] fp32, final output
    float* agg = (float*)d_ws;             // [L][T][B][D] fp32 = 25 MB

    rnn_kernel<<<dim3(NT * (NB / ROWS)), dim3(512), 0, stream>>>(emb, Wih, Whh, bih, bhh, nidx, agg);
    att_kernel<<<dim3(NB / 4), dim3(256), 0, stream>>>(emb, ids, watt, agg, cur, 0);
    att_kernel<<<dim3(NB / 4), dim3(256), 0, stream>>>(emb, ids, watt, agg, cur, 1);
}

// Round 19
// 77.280 us; speedup vs baseline: 1.2459x; 1.0152x over previous
//
#include <hip/hip_runtime.h>
#include <hip/hip_bf16.h>

#define NB   8192   // batch
#define NS   10     // neighbor seq len
#define NT   3      // node types
#define NN   65536  // table size
#define ND   128    // embed dim
#define NL   2      // layers
#define ROWS 32     // batch rows per block

typedef __attribute__((ext_vector_type(8))) short bf16x8;
typedef __attribute__((ext_vector_type(4))) float f32x4;

__device__ __forceinline__ unsigned int pk2(float lo, float hi) {
    unsigned int r;
    asm("v_cvt_pk_bf16_f32 %0, %1, %2" : "=v"(r) : "v"(lo), "v"(hi));
    return r;
}
// tanh(x) = 1 - 2/(exp2(2*log2e*x)+1)
__device__ __forceinline__ float tanh_f(float x) {
    float e, r;
    asm("v_exp_f32 %0, %1" : "=v"(e) : "v"(x * 2.88539004f));
    asm("v_rcp_f32 %0, %1" : "=v"(r) : "v"(e + 1.0f));
    return fmaf(-2.0f, r, 1.0f);
}
// Barrier with LDS-only drain: global (vmcnt) loads stay in flight across it.
__device__ __forceinline__ void bar_lgkm() {
    asm volatile("s_waitcnt lgkmcnt(0)\n\ts_barrier" ::: "memory");
}

// ---------------------------------------------------------------------------
// RNN kernel (r18 base + 2-deep gather prefetch + setprio): grid = NT*256
// blocks, 512 thr (8 waves = layer(2) x e-32(4)). Block owns (t, 32 rows),
// BOTH layers; X staged once/step for all 8 waves. r19 changes:
//  (a) PA/PB double-buffered gather: load used at step s+2 issues at step s
//      (~2 steps of latency cover; r18's 1-deep left the vmcnt wait at
//      pack-time ~50% exposed -> phase-locked convoy stall).
//  (b) s_setprio(1) around the MFMA cluster (T5: pays when waves role-split).
// Manual 2-step loop body keeps parity & P-buffer compile-time (rule #20)
// while bounding unroll bloat (r18: rolled=88 VGPR vs full-unroll=124).
// X + per-layer H double-buffered in LDS ([32][128] bf16, XOR-swizzled 16B
// chunks); ONE lgkm-only barrier per step. NO min-waves clause (r7/r10).
// ---------------------------------------------------------------------------
__global__ __launch_bounds__(512)
void rnn_kernel(const float* __restrict__ emb, const float* __restrict__ Wih,
                const float* __restrict__ Whh, const float* __restrict__ bih,
                const float* __restrict__ bhh, const int* __restrict__ nidx,
                float* __restrict__ agg)
{
    // [X p0 | X p1 | H(l0) p0 | H(l0) p1 | H(l1) p0 | H(l1) p1], 8 KB each
    __shared__ __align__(16) char lds[6 * 8192];

    const int bid = blockIdx.x;                 // NT * (NB/ROWS)
    const int t   = bid / (NB / ROWS);
    const int b0  = (bid % (NB / ROWS)) * ROWS;

    const int tid  = threadIdx.x;
    const int wv   = tid >> 6;
    const int lay  = wv >> 2;        // layer 0/1
    const int lane = tid & 63;
    const int l16  = lane & 15;
    const int lg   = lane >> 4;
    const int e0   = (wv & 3) * 32;  // e-slice within layer
    const int rx   = l16 & 7;        // read-swizzle key (rows stride 16)

    char* xb = lds;
    char* hb = lds + 16384 + lay * 16384;

    // staging geometry: 16 threads per row, 8 floats (one 16B bf16 chunk) each
    const int srow  = tid >> 4;      // 0..31
    const int sq    = tid & 15;      // chunk index
    const int xaddr = srow * 256 + ((sq ^ (srow & 7)) << 4);

    const int* ip = nidx + ((size_t)t * NB + b0 + srow) * NS;
    const float* ebase = emb + (size_t)t * NN * ND + sq * 8;

    // ---- 2-deep gather prefetch: issue s=0 and s=1 before W-frag build ----
    float4 PA0, PA1, PB0, PB1;
    {
        const float* sa = ebase + (size_t)ip[0] * ND;
        PA0 = *(const float4*)(sa);
        PA1 = *(const float4*)(sa + 4);
        const float* sb = ebase + (size_t)ip[1] * ND;
        PB0 = *(const float4*)(sb);
        PB1 = *(const float4*)(sb + 4);
    }
    int idx_a = ip[2];   // next even-step gather (s=2)
    int idx_b = ip[3];   // next odd-step gather  (s=3)

    const float* Wih_lt = Wih + (size_t)(lay * NT + t) * ND * ND;
    const float* Whh_lt = Whh + (size_t)(lay * NT + t) * ND * ND;
    const float* bih_lt = bih + (size_t)(lay * NT + t) * ND;
    const float* bhh_lt = bhh + (size_t)(lay * NT + t) * ND;

    // ---- A-fragments: rows e = e0 + mt*16 + l16, k-chunk kc (kc<4: Wih) ----
    bf16x8 Af[2][8];
    #pragma unroll
    for (int mt = 0; mt < 2; ++mt) {
        #pragma unroll
        for (int kc = 0; kc < 8; ++kc) {
            const float* Wsrc = (kc < 4) ? Wih_lt : Whh_lt;
            const float* srcp = Wsrc + (size_t)(e0 + mt * 16 + l16) * ND + (kc & 3) * 32 + lg * 8;
            float4 p0 = *(const float4*)(srcp);
            float4 p1 = *(const float4*)(srcp + 4);
            int4 a;
            a.x = (int)pk2(p0.x, p0.y);
            a.y = (int)pk2(p0.z, p0.w);
            a.z = (int)pk2(p1.x, p1.y);
            a.w = (int)pk2(p1.z, p1.w);
            Af[mt][kc] = *(bf16x8*)&a;
        }
    }

    // bias folded into MFMA C-init
    f32x4 biasv[2];
    #pragma unroll
    for (int mt = 0; mt < 2; ++mt) {
        int e = e0 + mt * 16 + lg * 4;
        float4 bi = *(const float4*)(bih_lt + e);
        float4 bh = *(const float4*)(bhh_lt + e);
        biasv[mt][0] = bi.x + bh.x;
        biasv[mt][1] = bi.y + bh.y;
        biasv[mt][2] = bi.z + bh.z;
        biasv[mt][3] = bi.w + bh.w;
    }

    // minimal precomputed LDS addressing (nt / parity folded at use sites)
    const int rowb = l16 * 256;
    int rdch[4];                     // read chunk offsets, shared X/H
    #pragma unroll
    for (int c = 0; c < 4; ++c)
        rdch[c] = ((c * 4 + lg) ^ rx) << 4;
    const int hw0 = ((((e0 >> 3) + (lg >> 1)) ^ rx) << 4) + (lg & 1) * 8;
    const int hw1 = ((((e0 >> 3) + 2 + (lg >> 1)) ^ rx) << 4) + (lg & 1) * 8;

    f32x4 zero4; zero4[0] = 0.f; zero4[1] = 0.f; zero4[2] = 0.f; zero4[3] = 0.f;
    f32x4 Ag[2][2];
    #pragma unroll
    for (int nt = 0; nt < 2; ++nt) { Ag[nt][0] = zero4; Ag[nt][1] = zero4; }

    #pragma unroll 1
    for (int s2 = 0; s2 < NS / 2; ++s2) {
        // ================= EVEN step s = 2*s2 (parity 0) =================
        {
            int4 pk;
            pk.x = (int)pk2(PA0.x, PA0.y);
            pk.y = (int)pk2(PA0.z, PA0.w);
            pk.z = (int)pk2(PA1.x, PA1.y);
            pk.w = (int)pk2(PA1.z, PA1.w);
            *(int4*)(xb + xaddr) = pk;
        }
        if (s2 < NS / 2 - 1) {                   // gather for s = 2*s2+2
            const float* src = ebase + (size_t)idx_a * ND;
            PA0 = *(const float4*)(src);
            PA1 = *(const float4*)(src + 4);
            idx_a = ip[(2 * s2 + 4 < NS) ? 2 * s2 + 4 : 0];
        }
        bar_lgkm();   // X_s & H_{s-1} visible; vmcnt (PB + new PA) in flight

        {
            f32x4 acc[2][2];
            #pragma unroll
            for (int nt = 0; nt < 2; ++nt) { acc[nt][0] = biasv[0]; acc[nt][1] = biasv[1]; }

            __builtin_amdgcn_s_setprio(1);
            #pragma unroll
            for (int nt = 0; nt < 2; ++nt)
                #pragma unroll
                for (int c = 0; c < 4; ++c) {
                    bf16x8 bf = *(const bf16x8*)(xb + rowb + rdch[c] + nt * 4096);
                    acc[nt][0] = __builtin_amdgcn_mfma_f32_16x16x32_bf16(Af[0][c], bf, acc[nt][0], 0, 0, 0);
                    acc[nt][1] = __builtin_amdgcn_mfma_f32_16x16x32_bf16(Af[1][c], bf, acc[nt][1], 0, 0, 0);
                }
            if (s2 > 0) {
                #pragma unroll
                for (int nt = 0; nt < 2; ++nt)
                    #pragma unroll
                    for (int c = 0; c < 4; ++c) {
                        bf16x8 bf = *(const bf16x8*)(hb + rowb + rdch[c] + nt * 4096 + 8192);
                        acc[nt][0] = __builtin_amdgcn_mfma_f32_16x16x32_bf16(Af[0][c + 4], bf, acc[nt][0], 0, 0, 0);
                        acc[nt][1] = __builtin_amdgcn_mfma_f32_16x16x32_bf16(Af[1][c + 4], bf, acc[nt][1], 0, 0, 0);
                    }
            }
            __builtin_amdgcn_s_setprio(0);

            #pragma unroll
            for (int nt = 0; nt < 2; ++nt) {
                f32x4 h0, h1;
                #pragma unroll
                for (int i = 0; i < 4; ++i) {
                    h0[i] = tanh_f(acc[nt][0][i]);
                    h1[i] = tanh_f(acc[nt][1][i]);
                }
                Ag[nt][0] += h0;
                Ag[nt][1] += h1;
                int2 pk0, pk1;
                pk0.x = (int)pk2(h0[0], h0[1]);
                pk0.y = (int)pk2(h0[2], h0[3]);
                pk1.x = (int)pk2(h1[0], h1[1]);
                pk1.y = (int)pk2(h1[2], h1[3]);
                *(int2*)(hb + rowb + hw0 + nt * 4096) = pk0;
                *(int2*)(hb + rowb + hw1 + nt * 4096) = pk1;
            }
        }

        // ================= ODD step s = 2*s2+1 (parity 1) =================
        {
            int4 pk;
            pk.x = (int)pk2(PB0.x, PB0.y);
            pk.y = (int)pk2(PB0.z, PB0.w);
            pk.z = (int)pk2(PB1.x, PB1.y);
            pk.w = (int)pk2(PB1.z, PB1.w);
            *(int4*)(xb + xaddr + 8192) = pk;
        }
        if (s2 < NS / 2 - 1) {                   // gather for s = 2*s2+3
            const float* src = ebase + (size_t)idx_b * ND;
            PB0 = *(const float4*)(src);
            PB1 = *(const float4*)(src + 4);
            idx_b = ip[(2 * s2 + 5 < NS) ? 2 * s2 + 5 : 0];
        }
        bar_lgkm();

        {
            f32x4 acc[2][2];
            #pragma unroll
            for (int nt = 0; nt < 2; ++nt) { acc[nt][0] = biasv[0]; acc[nt][1] = biasv[1]; }

            __builtin_amdgcn_s_setprio(1);
            #pragma unroll
            for (int nt = 0; nt < 2; ++nt)
                #pragma unroll
                for (int c = 0; c < 4; ++c) {
                    bf16x8 bf = *(const bf16x8*)(xb + rowb + rdch[c] + nt * 4096 + 8192);
                    acc[nt][0] = __builtin_amdgcn_mfma_f32_16x16x32_bf16(Af[0][c], bf, acc[nt][0], 0, 0, 0);
                    acc[nt][1] = __builtin_amdgcn_mfma_f32_16x16x32_bf16(Af[1][c], bf, acc[nt][1], 0, 0, 0);
                }
            #pragma unroll
            for (int nt = 0; nt < 2; ++nt)
                #pragma unroll
                for (int c = 0; c < 4; ++c) {
                    bf16x8 bf = *(const bf16x8*)(hb + rowb + rdch[c] + nt * 4096);
                    acc[nt][0] = __builtin_amdgcn_mfma_f32_16x16x32_bf16(Af[0][c + 4], bf, acc[nt][0], 0, 0, 0);
                    acc[nt][1] = __builtin_amdgcn_mfma_f32_16x16x32_bf16(Af[1][c + 4], bf, acc[nt][1], 0, 0, 0);
                }
            __builtin_amdgcn_s_setprio(0);

            #pragma unroll
            for (int nt = 0; nt < 2; ++nt) {
                f32x4 h0, h1;
                #pragma unroll
                for (int i = 0; i < 4; ++i) {
                    h0[i] = tanh_f(acc[nt][0][i]);
                    h1[i] = tanh_f(acc[nt][1][i]);
                }
                Ag[nt][0] += h0;
                Ag[nt][1] += h1;
                int2 pk0, pk1;
                pk0.x = (int)pk2(h0[0], h0[1]);
                pk0.y = (int)pk2(h0[2], h0[3]);
                pk1.x = (int)pk2(h1[0], h1[1]);
                pk1.y = (int)pk2(h1[2], h1[3]);
                *(int2*)(hb + rowb + hw0 + nt * 4096 + 8192) = pk0;
                *(int2*)(hb + rowb + hw1 + nt * 4096 + 8192) = pk1;
            }
        }
    }

    // agg[l][t][b][e]: lane writes float4 of 4 consecutive e at its rows
    float* aggp = agg + ((size_t)(lay * NT + t) * NB + b0) * ND;
    #pragma unroll
    for (int nt = 0; nt < 2; ++nt)
        #pragma unroll
        for (int mt = 0; mt < 2; ++mt) {
            f32x4 v = Ag[nt][mt] * 0.1f;
            *(f32x4*)(aggp + (size_t)(nt * 16 + l16) * ND + e0 + mt * 16 + lg * 4) = v;
        }
}

// ---------------------------------------------------------------------------
// Attention: one wave per batch row (lane covers d and d+64). 5 dots via
// shuffle reduce, softmax(4), weighted sum, leaky_relu. 2048 blocks x 256.
// ---------------------------------------------------------------------------
__global__ __launch_bounds__(256)
void att_kernel(const float* __restrict__ emb, const int* __restrict__ ids,
                const float* __restrict__ w_att, const float* __restrict__ agg,
                float* __restrict__ cur, const int l)
{
    const int wid  = threadIdx.x >> 6;
    const int lane = threadIdx.x & 63;
    const int b    = blockIdx.x * 4 + wid;

    const float* waH  = w_att + l * 2 * ND;
    const float* waT  = waH + ND;
    const float* crow = (l == 0) ? (emb + (size_t)ids[b] * ND) : (cur + (size_t)b * ND);
    const float* ab   = agg + ((size_t)(l * NT) * NB + b) * ND;   // + tt*NB*ND

    const float c1 = crow[lane], c2 = crow[lane + 64];
    const float h1 = waH[lane],  h2 = waH[lane + 64];
    const float t1 = waT[lane],  t2 = waT[lane + 64];
    float g1[3], g2[3];
    #pragma unroll
    for (int tt = 0; tt < 3; ++tt) {
        g1[tt] = ab[(size_t)tt * NB * ND + lane];
        g2[tt] = ab[(size_t)tt * NB * ND + lane + 64];
    }

    float dH = c1 * h1 + c2 * h2;
    float dc = c1 * t1 + c2 * t2;
    float d0 = g1[0] * t1 + g2[0] * t2;
    float d1 = g1[1] * t1 + g2[1] * t2;
    float d2 = g1[2] * t1 + g2[2] * t2;
    #pragma unroll
    for (int off = 32; off > 0; off >>= 1) {
        dH += __shfl_xor(dH, off);
        dc += __shfl_xor(dc, off);
        d0 += __shfl_xor(d0, off);
        d1 += __shfl_xor(d1, off);
        d2 += __shfl_xor(d2, off);
    }

    float s0 = dH + dc, s1 = dH + d0, s2 = dH + d1, s3 = dH + d2;
    float m  = fmaxf(fmaxf(s0, s1), fmaxf(s2, s3));
    float q0 = __expf(s0 - m), q1 = __expf(s1 - m), q2 = __expf(s2 - m), q3 = __expf(s3 - m);
    float inv = __fdividef(1.0f, q0 + q1 + q2 + q3);
    float w0 = q0 * inv, w1 = q1 * inv, w2 = q2 * inv, w3 = q3 * inv;

    float o1 = w0 * c1 + w1 * g1[0] + w2 * g1[1] + w3 * g1[2];
    float o2 = w0 * c2 + w1 * g2[0] + w2 * g2[1] + w3 * g2[2];
    o1 = (o1 > 0.f) ? o1 : 0.01f * o1;
    o2 = (o2 > 0.f) ? o2 : 0.01f * o2;

    float* orow = cur + (size_t)b * ND;
    orow[lane]      = o1;
    orow[lane + 64] = o2;
}

extern "C" void kernel_launch(void* const* d_in, const int* in_sizes, int n_in,
                              void* d_out, int out_size, void* d_ws, size_t ws_size,
                              hipStream_t stream)
{
    const float* emb  = (const float*)d_in[0];
    const float* Wih  = (const float*)d_in[1];
    const float* Whh  = (const float*)d_in[2];
    const float* bih  = (const float*)d_in[3];
    const float* bhh  = (const float*)d_in[4];
    const float* watt = (const float*)d_in[5];
    const int*   ids  = (const int*)d_in[6];
    const int*   nidx = (const int*)d_in[7];

    float* cur = (float*)d_out;            // [B][D] fp32, final output
    float* agg = (float*)d_ws;             // [L][T][B][D] fp32 = 25 MB

    rnn_kernel<<<dim3(NT * (NB / ROWS)), dim3(512), 0, stream>>>(emb, Wih, Whh, bih, bhh, nidx, agg);
    att_kernel<<<dim3(NB / 4), dim3(256), 0, stream>>>(emb, ids, watt, agg, cur, 0);
    att_kernel<<<dim3(NB / 4), dim3(256), 0, stream>>>(emb, ids, watt, agg, cur, 1);
}